// Round 11
// baseline (195.814 us; speedup 1.0000x reference)
//
#include <hip/hip_runtime.h>
#include <hip/hip_bf16.h>

#define BATCH 32
#define MAXPV 50
#define RN 256
#define PN 256
#define DIM 128
#define NI (BATCH*MAXPV)   // 1600 (b,pv) pairs

typedef unsigned short u16;
typedef __attribute__((ext_vector_type(8))) short short8;
typedef __attribute__((ext_vector_type(4))) float f32x4;

// ---- intermediates in the code object ----
__device__ float g_pa[NI*DIM], g_pb[NI*DIM], g_pc[NI*DIM];
__device__ float g_pp1[PN*DIM];
__device__ __attribute__((aligned(16))) float g_v[NI*DIM];    // normalized value rows
__device__ __attribute__((aligned(16))) float g_ra[RN*DIM];   // row-major [r][k]
__device__ __attribute__((aligned(16))) float g_rb[RN*DIM];   // row-major [r][k]
__device__ float g_rmask[RN], g_regp[RN];
__device__ float g_scores[(size_t)NI*RN];            // per-(i,r) contribution (pad rows only valid)
__device__ short8 g_bfrag[8][4][64];                 // fc6 B-frags [nt][ks][lane]
__device__ __attribute__((aligned(16))) float g_rcA[16*4*64*8]; // rc in MFMA-A layout [mt][ks][lane][8]

// d_ws layout (ints): [0]=nsame [1]=ndiff [2]=flags(bit0=bf16,bit1=i64) [3]=unused
// [4..1604): int wls[1600] = {i}   [1604..3204): int wld[1600] = {i}
#define WS_WLS(ws)  ((ws)+4)
#define WS_WLD(ws)  ((ws)+4+1600)

__device__ __forceinline__ float bf2f(u16 u){ return __uint_as_float(((unsigned)u)<<16); }
__device__ __forceinline__ float LD(const void* p, size_t i, bool bf){
    return bf ? bf2f(((const u16*)p)[i]) : ((const float*)p)[i];
}
__device__ __forceinline__ int LDI(const void* p, size_t i, bool w64){
    return w64 ? (int)((const long long*)p)[i] : ((const int*)p)[i];
}
__device__ __forceinline__ short f2bf(float f){
    unsigned u = __float_as_uint(f);
    u = (u + 0x7FFFu + ((u>>16)&1u)) >> 16;
    return (short)u;
}
__device__ __forceinline__ unsigned f2bf2(float x, float y){
    float2 f; f.x=x; f.y=y;
    __hip_bfloat162 h = __float22bfloat162_rn(f);      // v_cvt_pk_bf16_f32
    union { __hip_bfloat162 h; unsigned u; } c; c.h=h; return c.u;
}
// ---- per-block inline dtype detection (wave-uniform, ~6 insts) ----
__device__ __forceinline__ bool det_bf16(const void* ent){
    int l = threadIdx.x & 63;
    u16 v = ((const u16*)ent)[(size_t)2*(l*4)*977];    // max idx 492,408: safe both dtypes
    int e = (v>>7)&0xFF;
    return __popcll(__ballot(e>=120 && e<=133)) >= 48; // bf16 ~64/64, fp32 ~6/64
}
__device__ __forceinline__ bool det_i64(const void* prop){
    int l = threadIdx.x & 63;
    bool z = (l<32) ? (((const unsigned*)prop)[2*l+1]==0u) : false;
    return __popcll(__ballot(z)) >= 30;                // int64: 32/32 odd words zero
}
__device__ __forceinline__ float wred(float v){
#pragma unroll
    for(int o=32;o;o>>=1) v += __shfl_xor(v,o,64);
    return v;
}
__device__ __forceinline__ double wredd(double v){
#pragma unroll
    for(int o=32;o;o>>=1) v += __shfl_xor(v,o,64);
    return v;
}
__device__ __forceinline__ float wmax(float v){
#pragma unroll
    for(int o=32;o;o>>=1) v = fmaxf(v,__shfl_xor(v,o,64));
    return v;
}

// ---------------- A: fused gather+l2norm+row-matmuls + compaction + v-rows ----------------
// [0,100) pa | [100,200) pb | [200,300) pc | [300,316) ra | [316,332) rb
// [332,348) rcA | [348,364) pp1 | [364,372) bfrag pack (+init/flags on nt==0)
// [372,379) worklist compaction | [379,779) v-row gather+normalize
__global__ __launch_bounds__(256) void k_pre(
    const void* __restrict__ ent, const void* __restrict__ rule,
    const void* __restrict__ prop, const void* __restrict__ val,
    const void* __restrict__ same, const void* __restrict__ pad,
    const void* __restrict__ fc6w,
    const void* __restrict__ fc1w, const void* __restrict__ fc2w, const void* __restrict__ fc3w,
    const void* __restrict__ fc1b, const void* __restrict__ fc2b, const void* __restrict__ fc3b,
    int* __restrict__ ws){
    const bool bf = det_bf16(ent);
    const int blk = blockIdx.x, tid = threadIdx.x;
    if(blk >= 379){                                   // ---- v-row gather + l2norm ----
        const bool w64 = det_i64(prop);
        const int row = (blk-379)*4 + (tid>>6);
        const int l = tid & 63;
        size_t off = (size_t)LDI(val,row,w64)*DIM;
        float a = LD(ent,off+l,bf), b = LD(ent,off+l+64,bf);
        float n = fmaxf(sqrtf((float)wredd((double)a*a+(double)b*b)), 1e-12f);
        g_v[(size_t)row*DIM+l]=a/n; g_v[(size_t)row*DIM+l+64]=b/n;
        return;
    }
    if(blk >= 372){                                   // ---- worklist compaction ----
        const bool w64 = det_i64(prop);
        int i = (blk-372)*256 + tid;
        if(i < NI){
            int pd = LDI(pad,i,w64);
            if(pd==1){
                int sm = LDI(same,i,w64);
                if(sm==1){
                    int x = atomicAdd(ws+0,1);
                    WS_WLS(ws)[x] = i;
                } else {
                    int x = atomicAdd(ws+1,1);
                    WS_WLD(ws)[x] = i;
                }
            }
        }
        return;
    }
    if(blk >= 364){                                   // bfrag pack + accum init + flags
        int nt = blk-364;
        int ks = tid>>6, lane = tid&63;
        int n = nt*16 + (lane&15);
        int k0 = ks*32 + (lane>>4)*8;
        short8 v;
#pragma unroll
        for(int j=0;j<8;j++) v[j] = f2bf(LD(fc6w,(size_t)(k0+j)*DIM + n, bf));
        g_bfrag[nt][ks][lane] = v;
        if(nt==0){
            g_rmask[tid] = 1.f; g_regp[tid] = 0.f;
            const bool w64 = det_i64(prop);
            if(tid==0) ws[2] = (bf?1:0) | (w64?2:0);
        }
        return;
    }
    __shared__ float s_w[64*DIM];       // 32 KB (k-half of weights, fp32)
    __shared__ __attribute__((aligned(16))) float s_in[16*DIM]; // 8 KB
    __shared__ float s_bias[DIM];
    const void* w; size_t woff=0; const void* bptr=nullptr;
    float* out=nullptr; int row0; int mode=0; int srcsel;
    if(blk < 300){
        int wsel = blk/100; row0 = (blk%100)*16; srcsel = 0;
        w   = (wsel==0)?fc1w:(wsel==1)?fc2w:fc3w;
        out = (wsel==0)?g_pa:(wsel==1)?g_pb:g_pc;
    } else if(blk < 348){
        int rblk = blk-300; int wsel = rblk>>4; row0 = (rblk&15)*16; srcsel = 1;
        w    = (wsel==0)?fc1w:(wsel==1)?fc2w:fc3w;
        bptr = (wsel==0)?fc1b:(wsel==1)?fc2b:fc3b;
        woff = DIM*DIM; mode = wsel+1;
    } else { row0=(blk-348)*16; w=fc1w; out=g_pp1; srcsel=2; }
    // gather + l2norm the 16 input rows straight into LDS
    const bool w64 = (srcsel==0) ? det_i64(prop) : false;
    {
        const int l = tid & 63;
        for(int it=0; it<4; it++){
            int lr = it*4 + (tid>>6);
            int row = row0 + lr;
            const void* src; size_t off;
            if(srcsel==0){ src=ent;  off=(size_t)LDI(prop,row,w64)*DIM; }
            else if(srcsel==1){ src=rule; off=(size_t)row*DIM; }
            else { src=ent; off=(size_t)row*DIM; }
            float a = LD(src,off+l,bf), b = LD(src,off+l+64,bf);
            float n = fmaxf(sqrtf((float)wredd((double)a*a+(double)b*b)), 1e-12f);
            s_in[lr*DIM+l]=a/n; s_in[lr*DIM+l+64]=b/n;
        }
    }
    if(tid<DIM) s_bias[tid] = bptr ? LD(bptr,tid,bf) : 0.f;
    const int j = tid & 127;
    const int rb8 = (tid>>7)*8;
    double acc[8] = {0,0,0,0,0,0,0,0};
    for(int half=0; half<2; half++){
        __syncthreads();
        for(int t=tid; t<64*DIM; t+=256)
            s_w[t] = LD(w, woff + (size_t)(half*64 + (t>>7))*DIM + (t&127), bf);
        __syncthreads();
        for(int k=0;k<64;k+=4){                       // float4 s_in reads, same k-order
            const float w0 = s_w[(k+0)*DIM + j];
            const float w1 = s_w[(k+1)*DIM + j];
            const float w2 = s_w[(k+2)*DIM + j];
            const float w3 = s_w[(k+3)*DIM + j];
#pragma unroll
            for(int rr=0;rr<8;rr++){
                const float4 in4 = *(const float4*)&s_in[(rb8+rr)*DIM + half*64 + k];
                acc[rr] += (double)in4.x*(double)w0;
                acc[rr] += (double)in4.y*(double)w1;
                acc[rr] += (double)in4.z*(double)w2;
                acc[rr] += (double)in4.w*(double)w3;
            }
        }
    }
    const double bj = (double)s_bias[j];
#pragma unroll
    for(int rr=0;rr<8;rr++){
        const int row = row0 + rb8 + rr;
        const float vv = (float)(bj + acc[rr]);
        if(mode==0)      out[(size_t)row*DIM + j] = vv;
        else if(mode==1) g_ra[(size_t)row*DIM + j] = vv;   // row-major
        else if(mode==2) g_rb[(size_t)row*DIM + j] = vv;   // row-major
        else {           // rcA scatter: row in [0,256), k=j
            int mt=row>>4, am=row&15, ks=j>>5, quad=(j>>3)&3, jj=j&7;
            g_rcA[((mt*4+ks)*64 + quad*16+am)*8 + jj] = vv;
        }
    }
}

// ---------------- B: fused gates + MFMA scoring (grid-driven, 4-wave gate split) ----------------
// [0,64): pi items | [64, 64+4*nsame): MFMA quarters | then 2*ndiff diff half-items
__global__ __launch_bounds__(256) void k_score(
    const void* __restrict__ fc4w, const void* __restrict__ fc4b,
    const void* __restrict__ fc5w, const void* __restrict__ fc5b,
    const void* __restrict__ fc6b, const int* __restrict__ ws){
    const int blk = blockIdx.x, tid = threadIdx.x;
    const int fl = ws[2];
    const bool bf = fl & 1;
    if(blk < 64){                                      // ---- pi item ----
        __shared__ float s_a[4][DIM];
        __shared__ double s_pf4[DIM];
        const int i0 = blk*4;
        if(tid<DIM) s_pf4[tid]=(double)LD(fc4w,tid,bf);
        for(int t=tid; t<4*DIM; t+=256){
            int ii=t>>7, k=t&127;
            s_a[ii][k] = g_pp1[(size_t)(i0+ii)*DIM+k];
        }
        __syncthreads();
        const int r = tid;
        const float4* rap = (const float4*)&g_ra[(size_t)r*DIM];
        double d0=0.0, d1=0.0, d2=0.0, d3=0.0;
#pragma unroll 8
        for(int x=0; x<32; x++){                       // k = 4x..4x+3, ascending
            const float4 ra = rap[x];
#pragma unroll
            for(int cc=0; cc<4; cc++){
                const int k = x*4 + cc;
                const float rav = (cc==0)?ra.x:(cc==1)?ra.y:(cc==2)?ra.z:ra.w;
                const double f4k = s_pf4[k];
                d0 += (double)fmaxf(s_a[0][k]+rav,0.f)*f4k;
                d1 += (double)fmaxf(s_a[1][k]+rav,0.f)*f4k;
                d2 += (double)fmaxf(s_a[2][k]+rav,0.f)*f4k;
                d3 += (double)fmaxf(s_a[3][k]+rav,0.f)*f4k;
            }
        }
        const double b4 = (double)LD(fc4b,0,bf);
        double d[4] = {d0,d1,d2,d3};
        float mask_sum = 0.f, reg_sum = 0.f;
#pragma unroll
        for(int ii=0;ii<4;ii++){
            int p = i0 + ii;
            double sd = d[ii] + b4;
            float piv = 1.f/(1.f+expf(-(float)sd));
            if(sd > 0.0) mask_sum += piv;              // piv>0.5 <=> sd>0
            float eff = (p==r) ? piv : (1.f - piv);
            float wgt = (p==r) ? (float)RN : 1.f;
            reg_sum += -logf(eff + 1e-8f)*wgt;
        }
        atomicAdd(&g_rmask[r], mask_sum);
        atomicAdd(&g_regp[r], reg_sum);
        return;
    }
    int w2 = blk - 64;
    const int ns4 = ws[0]*4;

    __shared__ float s_pa[DIM], s_pb[DIM], s_pc[DIM], s_v[DIM], s_f4[DIM], s_f5[DIM];
    __shared__ double s_gd[2][64];
    __shared__ float s_gq[2][64];
    __shared__ double s_pd[2][128];
    __shared__ float s_s1[64], s_p[64];
    __shared__ float s_st[64][4][2];       // 2 KB

    if(w2 >= ns4){                                     // ---- diff half-item (128 r, k split) ----
        int t2 = w2 - ns4;
        if(t2 >= 2*ws[1]) return;
        const int i = WS_WLD(ws)[t2>>1];
        const int sub = t2 & 1;
        if(tid < 128){
            s_pa[tid] = g_pa[(size_t)i*DIM + tid];
            s_f4[tid] = LD(fc4w,tid,bf);
        }
        __syncthreads();
        const int rr = tid & 127, half = tid >> 7;
        const int r = sub*128 + rr;
        const float4* rap = (const float4*)&g_ra[(size_t)r*DIM + half*64];
        double d = 0.0;
#pragma unroll 8
        for(int x=0; x<16; x++){                       // k = half*64 + 4x.., ascending
            const float4 ra = rap[x];
            const int k = half*64 + x*4;
            d += (double)fmaxf(s_pa[k+0]+ra.x,0.f)*(double)s_f4[k+0];
            d += (double)fmaxf(s_pa[k+1]+ra.y,0.f)*(double)s_f4[k+1];
            d += (double)fmaxf(s_pa[k+2]+ra.z,0.f)*(double)s_f4[k+2];
            d += (double)fmaxf(s_pa[k+3]+ra.w,0.f)*(double)s_f4[k+3];
        }
        s_pd[half][rr] = d;
        __syncthreads();
        if(tid < 128){
            const double b4 = (double)LD(fc4b,0,bf);
            double sd = (s_pd[0][tid] + s_pd[1][tid]) + b4;
            float s1v = 1.f/(1.f+expf(-(float)sd));
            g_scores[(size_t)i*RN + sub*128 + tid] = (sd > 0.0) ? (1.f - s1v) : 0.f;
        }
        return;
    }

    // ---- MFMA quarter: q4 in [0,4), covers mt = q4*4..q4*4+3, rows r = q4*64..+64 ----
    const int i = WS_WLS(ws)[w2>>2];
    const int q4 = w2 & 3;

    if(tid < DIM){                          // stage rows + gate weights
        s_pa[tid] = g_pa[(size_t)i*DIM + tid];
        s_pb[tid] = g_pb[(size_t)i*DIM + tid];
        s_pc[tid] = g_pc[(size_t)i*DIM + tid];
        s_f4[tid] = LD(fc4w,tid,bf);
        s_f5[tid] = LD(fc5w,tid,bf);
    } else if(tid < 192){                   // stage precomputed v-row
        const int ll = tid - 128;
        s_v[ll]    = g_v[(size_t)i*DIM + ll];
        s_v[ll+64] = g_v[(size_t)i*DIM + ll + 64];
    }

    // ---- early issue of MFMA B-operands + fc6b (covered by gate compute) ----
    const int w = tid>>6, l = tid&63;
    const int am = l&15, quad = l>>4;
    short8 bA[4], bB[4];
#pragma unroll
    for(int ks=0; ks<4; ks++){ bA[ks]=g_bfrag[2*w][ks][l]; bB[ks]=g_bfrag[2*w+1][ks][l]; }
    const int n0 = w*32 + am, n1 = n0 + 16;
    const float b60 = LD(fc6b, n0, bf), b61 = LD(fc6b, n1, bf);
    __syncthreads();

    // ---- gate phase: all 4 waves, k split in halves, exact per-half k-order ----
    const int rr = tid & 63, wv = tid >> 6;
    const int r = q4*64 + rr;
    if(wv < 2){                             // d partial (f64), half = wv
        const float4* rap = (const float4*)&g_ra[(size_t)r*DIM + wv*64];
        double d = 0.0;
#pragma unroll 8
        for(int x=0; x<16; x++){
            const float4 ra = rap[x];
            const int k = wv*64 + x*4;
            d += (double)fmaxf(s_pa[k+0]+ra.x,0.f)*(double)s_f4[k+0];
            d += (double)fmaxf(s_pa[k+1]+ra.y,0.f)*(double)s_f4[k+1];
            d += (double)fmaxf(s_pa[k+2]+ra.z,0.f)*(double)s_f4[k+2];
            d += (double)fmaxf(s_pa[k+3]+ra.w,0.f)*(double)s_f4[k+3];
        }
        s_gd[wv][rr] = d;
    } else {                                // pq partial (f32), half = wv-2
        const int hh = wv - 2;
        const float4* rbp = (const float4*)&g_rb[(size_t)r*DIM + hh*64];
        float pq = 0.f;
#pragma unroll 8
        for(int x=0; x<16; x++){
            const float4 rb = rbp[x];
            const int k = hh*64 + x*4;
            pq = fmaf(fmaxf(s_pb[k+0]+rb.x,0.f), s_f5[k+0], pq);
            pq = fmaf(fmaxf(s_pb[k+1]+rb.y,0.f), s_f5[k+1], pq);
            pq = fmaf(fmaxf(s_pb[k+2]+rb.z,0.f), s_f5[k+2], pq);
            pq = fmaf(fmaxf(s_pb[k+3]+rb.w,0.f), s_f5[k+3], pq);
        }
        s_gq[hh][rr] = pq;
    }
    __syncthreads();
    if(tid < 64){
        const double b4 = (double)LD(fc4b,0,bf);
        double sd = (s_gd[0][tid] + s_gd[1][tid]) + b4;
        float s1v = 1.f/(1.f+expf(-(float)sd));
        s_s1[tid] = (sd > 0.0) ? s1v : -s1v;
    } else if(tid < 128){
        const float b5 = LD(fc5b,0,bf);
        float pq = s_gq[0][tid-64] + s_gq[1][tid-64];
        s_p[tid-64] = 1.f/(1.f+expf(-(pq + b5)));
    }
    __syncthreads();                        // s_s1/s_p ready

    // ---- MFMA phase (r8 prefetch structure, 4 tiles) ----
    const float v0 = s_v[n0], v1 = s_v[n1];
    float vl = s_v[l], vh = s_v[l+64];
    const float nvb = sqrtf(wred(vl*vl + vh*vh));

    int mt = q4*4;
    float4 c[8];
#pragma unroll
    for(int ks=0; ks<4; ks++){
        const float* rp = &g_rcA[((mt*4+ks)*64 + l)*8];
        c[2*ks]   = *(const float4*)rp;
        c[2*ks+1] = *(const float4*)(rp+4);
    }
    for(int mtl=0; mtl<4; mtl++){
        float4 n[8];
        if(mtl < 3){
#pragma unroll
            for(int ks=0; ks<4; ks++){
                const float* rp = &g_rcA[(((mt+1)*4+ks)*64 + l)*8];
                n[2*ks]   = *(const float4*)rp;
                n[2*ks+1] = *(const float4*)(rp+4);
            }
        }
        short8 a[4];
#pragma unroll
        for(int ks=0; ks<4; ks++){
            const float4 p0 = *(const float4*)&s_pc[ks*32 + quad*8];
            const float4 p1 = *(const float4*)&s_pc[ks*32 + quad*8 + 4];
            const float4 c0 = c[2*ks], c1 = c[2*ks+1];
            union { short8 s; unsigned u[4]; } t;
            t.u[0] = f2bf2(fmaxf(p0.x+c0.x,0.f), fmaxf(p0.y+c0.y,0.f));
            t.u[1] = f2bf2(fmaxf(p0.z+c0.z,0.f), fmaxf(p0.w+c0.w,0.f));
            t.u[2] = f2bf2(fmaxf(p1.x+c1.x,0.f), fmaxf(p1.y+c1.y,0.f));
            t.u[3] = f2bf2(fmaxf(p1.z+c1.z,0.f), fmaxf(p1.w+c1.w,0.f));
            a[ks] = t.s;
        }
        f32x4 acc0 = {0.f,0.f,0.f,0.f}, acc1 = {0.f,0.f,0.f,0.f};
#pragma unroll
        for(int ks=0; ks<4; ks++){
            acc0 = __builtin_amdgcn_mfma_f32_16x16x32_bf16(a[ks], bA[ks], acc0, 0,0,0);
            acc1 = __builtin_amdgcn_mfma_f32_16x16x32_bf16(a[ks], bB[ks], acc1, 0,0,0);
        }
#pragma unroll
        for(int q=0; q<4; q++){
            float x0 = acc0[q] + b60;
            float x1 = acc1[q] + b61;
            float ss = x0*x0 + x1*x1;
            float dv = x0*v0 + x1*v1;
#pragma unroll
            for(int o=1;o<16;o<<=1){ ss += __shfl_xor(ss,o,64); dv += __shfl_xor(dv,o,64); }
            if(am==0){
                int row = mtl*16 + quad*4 + q;
                s_st[row][w][0] = ss;
                s_st[row][w][1] = dv;
            }
        }
#pragma unroll
        for(int x=0;x<8;x++) c[x] = n[x];
        mt++;
    }
    __syncthreads();
    if(tid < 64){
        const int r2 = q4*64 + tid;
        float ss = s_st[tid][0][0]+s_st[tid][1][0]+s_st[tid][2][0]+s_st[tid][3][0];
        float dv = s_st[tid][0][1]+s_st[tid][1][1]+s_st[tid][2][1]+s_st[tid][3][1];
        float s1 = fabsf(s_s1[tid]);
        float gate = (s_s1[tid] > 0.f) ? 1.f : 0.f;
        float pp = s_p[tid];
        float nx = sqrtf(ss);
        float clipnx = fmaxf(nx, 1e-12f);
        float gvn = nx/clipnx;
        float denom = fmaxf(nvb*gvn, 1e-8f);
        float cosv = (dv/clipnx)/denom;
        float s2 = 0.5f*cosv + 0.5f;
        float sc = s1*(pp + (1.f-pp)*s2);
        g_scores[(size_t)i*RN + r2] = sc * gate;
    }
}

// ---------------- C: pooled max + reg mean ----------------
__global__ void k_fin(float* __restrict__ out, const void* __restrict__ pad,
                      const int* __restrict__ ws){
    const bool w64 = (ws[2] & 2) != 0;
    const int blk = blockIdx.x, tid = threadIdx.x;
    const int w = tid>>6, l = tid&63;
    __shared__ float s[4];
    if(blk < 32){
        __shared__ int s_pad[MAXPV];
        if(tid < MAXPV) s_pad[tid] = LDI(pad, (size_t)blk*MAXPV + tid, w64);
        __syncthreads();
        float ssum = 0.f;
        for(int pv=0; pv<MAXPV; pv++){
            if(!s_pad[pv]) continue;
            ssum += g_scores[((size_t)blk*MAXPV + pv)*RN + tid];
        }
        float sc = ssum / g_rmask[tid];
        float m = wmax(sc);
        if(l==0) s[w]=m;
        __syncthreads();
        if(tid==0) out[blk] = fmaxf(fmaxf(s[0],s[1]), fmaxf(s[2],s[3]));
    } else {
        float v = g_regp[tid];
        v = wred(v);
        if(l==0) s[w]=v;
        __syncthreads();
        if(tid==0) out[32] = (s[0]+s[1]+s[2]+s[3]) / (float)(RN*PN);
    }
}

extern "C" void kernel_launch(void* const* d_in, const int* in_sizes, int n_in,
                              void* d_out, int out_size, void* d_ws, size_t ws_size,
                              hipStream_t stream){
    int map[18]; for(int i=0;i<18;i++) map[i]=i;
    if(n_in>=18 && in_sizes[0]==6400000){
        const int a[18] = {14,17,16,13,15,0,2,1,4,3,6,5,8,7,10,9,12,11};
        for(int i=0;i<18;i++) map[i]=a[i];
    }
    const void* prop = d_in[map[0]];
    const void* val  = d_in[map[1]];
    const void* same = d_in[map[2]];
    const void* pad  = d_in[map[3]];
    const void* rule = d_in[map[4]];
    const void* ent  = d_in[map[5]];
    const void* fc1w = d_in[map[6]];
    const void* fc1b = d_in[map[7]];
    const void* fc2w = d_in[map[8]];
    const void* fc2b = d_in[map[9]];
    const void* fc3w = d_in[map[10]];
    const void* fc3b = d_in[map[11]];
    const void* fc4w = d_in[map[12]];
    const void* fc4b = d_in[map[13]];
    const void* fc5w = d_in[map[14]];
    const void* fc5b = d_in[map[15]];
    const void* fc6w = d_in[map[16]];
    const void* fc6b = d_in[map[17]];

    hipMemsetAsync(d_ws, 0, 16, stream);   // zero worklist counters + flags
    k_pre<<<779, 256, 0, stream>>>(ent, rule, prop, val, same, pad, fc6w,
                                   fc1w, fc2w, fc3w, fc1b, fc2b, fc3b, (int*)d_ws);
    k_score<<<64 + 6*NI, 256, 0, stream>>>(fc4w, fc4b, fc5w, fc5b, fc6b,
                                           (const int*)d_ws);
    k_fin<<<33, 256, 0, stream>>>((float*)d_out, pad, (const int*)d_ws);
}

// Round 12
// 182.865 us; speedup vs baseline: 1.0708x; 1.0708x over previous
//
#include <hip/hip_runtime.h>
#include <hip/hip_bf16.h>

#define BATCH 32
#define MAXPV 50
#define RN 256
#define PN 256
#define DIM 128
#define NI (BATCH*MAXPV)   // 1600 (b,pv) pairs

typedef unsigned short u16;
typedef __attribute__((ext_vector_type(8))) short short8;
typedef __attribute__((ext_vector_type(4))) float f32x4;

// ---- intermediates in the code object ----
__device__ float g_pa[NI*DIM], g_pb[NI*DIM], g_pc[NI*DIM];
__device__ float g_pp1[PN*DIM];
__device__ __attribute__((aligned(16))) float g_v[NI*DIM];    // normalized value rows
__device__ __attribute__((aligned(16))) float g_ra[RN*DIM];   // row-major [r][k]
__device__ __attribute__((aligned(16))) float g_rb[RN*DIM];   // row-major [r][k]
__device__ float g_rmask[RN], g_regp[RN];
__device__ float g_scores[(size_t)NI*RN];            // per-(i,r) contribution (pad rows only valid)
__device__ short8 g_bfrag[8][4][64];                 // fc6 B-frags [nt][ks][lane]
__device__ __attribute__((aligned(16))) float g_rcA[16*4*64*8]; // rc in MFMA-A layout [mt][ks][lane][8]

// d_ws layout (ints): [0]=nsame [1]=ndiff [2]=flags(bit0=bf16,bit1=i64) [3]=unused
// [4..1604): int wls[1600] = {i}   [1604..3204): int wld[1600] = {i}
#define WS_WLS(ws)  ((ws)+4)
#define WS_WLD(ws)  ((ws)+4+1600)

__device__ __forceinline__ float bf2f(u16 u){ return __uint_as_float(((unsigned)u)<<16); }
__device__ __forceinline__ float LD(const void* p, size_t i, bool bf){
    return bf ? bf2f(((const u16*)p)[i]) : ((const float*)p)[i];
}
__device__ __forceinline__ int LDI(const void* p, size_t i, bool w64){
    return w64 ? (int)((const long long*)p)[i] : ((const int*)p)[i];
}
__device__ __forceinline__ short f2bf(float f){
    unsigned u = __float_as_uint(f);
    u = (u + 0x7FFFu + ((u>>16)&1u)) >> 16;
    return (short)u;
}
__device__ __forceinline__ unsigned f2bf2(float x, float y){
    float2 f; f.x=x; f.y=y;
    __hip_bfloat162 h = __float22bfloat162_rn(f);      // v_cvt_pk_bf16_f32
    union { __hip_bfloat162 h; unsigned u; } c; c.h=h; return c.u;
}
// ---- per-block inline dtype detection (wave-uniform, ~6 insts) ----
__device__ __forceinline__ bool det_bf16(const void* ent){
    int l = threadIdx.x & 63;
    u16 v = ((const u16*)ent)[(size_t)2*(l*4)*977];    // max idx 492,408: safe both dtypes
    int e = (v>>7)&0xFF;
    return __popcll(__ballot(e>=120 && e<=133)) >= 48; // bf16 ~64/64, fp32 ~6/64
}
__device__ __forceinline__ bool det_i64(const void* prop){
    int l = threadIdx.x & 63;
    bool z = (l<32) ? (((const unsigned*)prop)[2*l+1]==0u) : false;
    return __popcll(__ballot(z)) >= 30;                // int64: 32/32 odd words zero
}
__device__ __forceinline__ float wred(float v){
#pragma unroll
    for(int o=32;o;o>>=1) v += __shfl_xor(v,o,64);
    return v;
}
__device__ __forceinline__ double wredd(double v){
#pragma unroll
    for(int o=32;o;o>>=1) v += __shfl_xor(v,o,64);
    return v;
}
__device__ __forceinline__ float wmax(float v){
#pragma unroll
    for(int o=32;o;o>>=1) v = fmaxf(v,__shfl_xor(v,o,64));
    return v;
}

// ---------------- A: fused gather+l2norm+row-matmuls + compaction + v-rows ----------------
// [0,100) pa | [100,200) pb | [200,300) pc | [300,316) ra | [316,332) rb
// [332,348) rcA | [348,364) pp1 | [364,372) bfrag pack (+init/flags on nt==0)
// [372,379) worklist compaction | [379,779) v-row gather+normalize
__global__ __launch_bounds__(256) void k_pre(
    const void* __restrict__ ent, const void* __restrict__ rule,
    const void* __restrict__ prop, const void* __restrict__ val,
    const void* __restrict__ same, const void* __restrict__ pad,
    const void* __restrict__ fc6w,
    const void* __restrict__ fc1w, const void* __restrict__ fc2w, const void* __restrict__ fc3w,
    const void* __restrict__ fc1b, const void* __restrict__ fc2b, const void* __restrict__ fc3b,
    int* __restrict__ ws){
    const bool bf = det_bf16(ent);
    const int blk = blockIdx.x, tid = threadIdx.x;
    if(blk >= 379){                                   // ---- v-row gather + l2norm ----
        const bool w64 = det_i64(prop);
        const int row = (blk-379)*4 + (tid>>6);
        const int l = tid & 63;
        size_t off = (size_t)LDI(val,row,w64)*DIM;
        float a = LD(ent,off+l,bf), b = LD(ent,off+l+64,bf);
        float n = fmaxf(sqrtf((float)wredd((double)a*a+(double)b*b)), 1e-12f);
        g_v[(size_t)row*DIM+l]=a/n; g_v[(size_t)row*DIM+l+64]=b/n;
        return;
    }
    if(blk >= 372){                                   // ---- worklist compaction ----
        const bool w64 = det_i64(prop);
        int i = (blk-372)*256 + tid;
        if(i < NI){
            int pd = LDI(pad,i,w64);
            if(pd==1){
                int sm = LDI(same,i,w64);
                if(sm==1){
                    int x = atomicAdd(ws+0,1);
                    WS_WLS(ws)[x] = i;
                } else {
                    int x = atomicAdd(ws+1,1);
                    WS_WLD(ws)[x] = i;
                }
            }
        }
        return;
    }
    if(blk >= 364){                                   // bfrag pack + accum init + flags
        int nt = blk-364;
        int ks = tid>>6, lane = tid&63;
        int n = nt*16 + (lane&15);
        int k0 = ks*32 + (lane>>4)*8;
        short8 v;
#pragma unroll
        for(int j=0;j<8;j++) v[j] = f2bf(LD(fc6w,(size_t)(k0+j)*DIM + n, bf));
        g_bfrag[nt][ks][lane] = v;
        if(nt==0){
            g_rmask[tid] = 1.f; g_regp[tid] = 0.f;
            const bool w64 = det_i64(prop);
            if(tid==0) ws[2] = (bf?1:0) | (w64?2:0);
        }
        return;
    }
    __shared__ float s_w[64*DIM];       // 32 KB (k-half of weights, fp32)
    __shared__ __attribute__((aligned(16))) float s_in[16*DIM]; // 8 KB
    __shared__ float s_bias[DIM];
    const void* w; size_t woff=0; const void* bptr=nullptr;
    float* out=nullptr; int row0; int mode=0; int srcsel;
    if(blk < 300){
        int wsel = blk/100; row0 = (blk%100)*16; srcsel = 0;
        w   = (wsel==0)?fc1w:(wsel==1)?fc2w:fc3w;
        out = (wsel==0)?g_pa:(wsel==1)?g_pb:g_pc;
    } else if(blk < 348){
        int rblk = blk-300; int wsel = rblk>>4; row0 = (rblk&15)*16; srcsel = 1;
        w    = (wsel==0)?fc1w:(wsel==1)?fc2w:fc3w;
        bptr = (wsel==0)?fc1b:(wsel==1)?fc2b:fc3b;
        woff = DIM*DIM; mode = wsel+1;
    } else { row0=(blk-348)*16; w=fc1w; out=g_pp1; srcsel=2; }
    // gather + l2norm the 16 input rows straight into LDS
    const bool w64 = (srcsel==0) ? det_i64(prop) : false;
    {
        const int l = tid & 63;
        for(int it=0; it<4; it++){
            int lr = it*4 + (tid>>6);
            int row = row0 + lr;
            const void* src; size_t off;
            if(srcsel==0){ src=ent;  off=(size_t)LDI(prop,row,w64)*DIM; }
            else if(srcsel==1){ src=rule; off=(size_t)row*DIM; }
            else { src=ent; off=(size_t)row*DIM; }
            float a = LD(src,off+l,bf), b = LD(src,off+l+64,bf);
            float n = fmaxf(sqrtf((float)wredd((double)a*a+(double)b*b)), 1e-12f);
            s_in[lr*DIM+l]=a/n; s_in[lr*DIM+l+64]=b/n;
        }
    }
    if(tid<DIM) s_bias[tid] = bptr ? LD(bptr,tid,bf) : 0.f;
    const int j = tid & 127;
    const int rb8 = (tid>>7)*8;
    double acc[8] = {0,0,0,0,0,0,0,0};
    for(int half=0; half<2; half++){
        __syncthreads();
        for(int t=tid; t<64*DIM; t+=256)
            s_w[t] = LD(w, woff + (size_t)(half*64 + (t>>7))*DIM + (t&127), bf);
        __syncthreads();
        for(int k=0;k<64;k+=4){                       // float4 s_in reads, same k-order
            const float w0 = s_w[(k+0)*DIM + j];
            const float w1 = s_w[(k+1)*DIM + j];
            const float w2 = s_w[(k+2)*DIM + j];
            const float w3 = s_w[(k+3)*DIM + j];
#pragma unroll
            for(int rr=0;rr<8;rr++){
                const float4 in4 = *(const float4*)&s_in[(rb8+rr)*DIM + half*64 + k];
                acc[rr] += (double)in4.x*(double)w0;
                acc[rr] += (double)in4.y*(double)w1;
                acc[rr] += (double)in4.z*(double)w2;
                acc[rr] += (double)in4.w*(double)w3;
            }
        }
    }
    const double bj = (double)s_bias[j];
#pragma unroll
    for(int rr=0;rr<8;rr++){
        const int row = row0 + rb8 + rr;
        const float vv = (float)(bj + acc[rr]);
        if(mode==0)      out[(size_t)row*DIM + j] = vv;
        else if(mode==1) g_ra[(size_t)row*DIM + j] = vv;   // row-major
        else if(mode==2) g_rb[(size_t)row*DIM + j] = vv;   // row-major
        else {           // rcA scatter: row in [0,256), k=j
            int mt=row>>4, am=row&15, ks=j>>5, quad=(j>>3)&3, jj=j&7;
            g_rcA[((mt*4+ks)*64 + quad*16+am)*8 + jj] = vv;
        }
    }
}

// ---------------- B: fused gates + MFMA scoring (grid-driven, 4-wave gate split) ----------------
// [0,64): pi items | [64, 64+4*nsame): MFMA quarters | then 2*ndiff diff half-items
__global__ __launch_bounds__(256) void k_score(
    const void* __restrict__ fc4w, const void* __restrict__ fc4b,
    const void* __restrict__ fc5w, const void* __restrict__ fc5b,
    const void* __restrict__ fc6b, const int* __restrict__ ws){
    const int blk = blockIdx.x, tid = threadIdx.x;
    const int fl = ws[2];
    const bool bf = fl & 1;
    if(blk < 64){                                      // ---- pi item ----
        __shared__ float s_a[4][DIM];
        __shared__ double s_pf4[DIM];
        const int i0 = blk*4;
        if(tid<DIM) s_pf4[tid]=(double)LD(fc4w,tid,bf);
        for(int t=tid; t<4*DIM; t+=256){
            int ii=t>>7, k=t&127;
            s_a[ii][k] = g_pp1[(size_t)(i0+ii)*DIM+k];
        }
        __syncthreads();
        const int r = tid;
        const float4* rap = (const float4*)&g_ra[(size_t)r*DIM];
        double d0=0.0, d1=0.0, d2=0.0, d3=0.0;
#pragma unroll 4
        for(int x=0; x<32; x++){                       // k = 4x..4x+3, ascending
            const float4 ra = rap[x];
#pragma unroll
            for(int cc=0; cc<4; cc++){
                const int k = x*4 + cc;
                const float rav = (cc==0)?ra.x:(cc==1)?ra.y:(cc==2)?ra.z:ra.w;
                const double f4k = s_pf4[k];
                d0 += (double)fmaxf(s_a[0][k]+rav,0.f)*f4k;
                d1 += (double)fmaxf(s_a[1][k]+rav,0.f)*f4k;
                d2 += (double)fmaxf(s_a[2][k]+rav,0.f)*f4k;
                d3 += (double)fmaxf(s_a[3][k]+rav,0.f)*f4k;
            }
        }
        const double b4 = (double)LD(fc4b,0,bf);
        double d[4] = {d0,d1,d2,d3};
        float mask_sum = 0.f, reg_sum = 0.f;
#pragma unroll
        for(int ii=0;ii<4;ii++){
            int p = i0 + ii;
            double sd = d[ii] + b4;
            float piv = 1.f/(1.f+expf(-(float)sd));
            if(sd > 0.0) mask_sum += piv;              // piv>0.5 <=> sd>0
            float eff = (p==r) ? piv : (1.f - piv);
            float wgt = (p==r) ? (float)RN : 1.f;
            reg_sum += -logf(eff + 1e-8f)*wgt;
        }
        atomicAdd(&g_rmask[r], mask_sum);
        atomicAdd(&g_regp[r], reg_sum);
        return;
    }
    int w2 = blk - 64;
    const int ns4 = ws[0]*4;

    __shared__ float s_pa[DIM], s_pb[DIM], s_pc[DIM], s_v[DIM], s_f4[DIM], s_f5[DIM];
    __shared__ double s_gd[2][64];
    __shared__ float s_gq[2][64];
    __shared__ double s_pd[2][128];
    __shared__ float s_s1[64], s_p[64];
    __shared__ float s_st[64][4][2];       // 2 KB

    if(w2 >= ns4){                                     // ---- diff half-item (128 r, k split) ----
        int t2 = w2 - ns4;
        if(t2 >= 2*ws[1]) return;
        const int i = WS_WLD(ws)[t2>>1];
        const int sub = t2 & 1;
        if(tid < 128){
            s_pa[tid] = g_pa[(size_t)i*DIM + tid];
            s_f4[tid] = LD(fc4w,tid,bf);
        }
        __syncthreads();
        const int rr = tid & 127, half = tid >> 7;
        const int r = sub*128 + rr;
        const float4* rap = (const float4*)&g_ra[(size_t)r*DIM + half*64];
        double d = 0.0;
#pragma unroll 4
        for(int x=0; x<16; x++){                       // k = half*64 + 4x.., ascending
            const float4 ra = rap[x];
            const int k = half*64 + x*4;
            d += (double)fmaxf(s_pa[k+0]+ra.x,0.f)*(double)s_f4[k+0];
            d += (double)fmaxf(s_pa[k+1]+ra.y,0.f)*(double)s_f4[k+1];
            d += (double)fmaxf(s_pa[k+2]+ra.z,0.f)*(double)s_f4[k+2];
            d += (double)fmaxf(s_pa[k+3]+ra.w,0.f)*(double)s_f4[k+3];
        }
        s_pd[half][rr] = d;
        __syncthreads();
        if(tid < 128){
            const double b4 = (double)LD(fc4b,0,bf);
            double sd = (s_pd[0][tid] + s_pd[1][tid]) + b4;
            float s1v = 1.f/(1.f+expf(-(float)sd));
            g_scores[(size_t)i*RN + sub*128 + tid] = (sd > 0.0) ? (1.f - s1v) : 0.f;
        }
        return;
    }

    // ---- MFMA quarter: q4 in [0,4), covers mt = q4*4..q4*4+3, rows r = q4*64..+64 ----
    const int i = WS_WLS(ws)[w2>>2];
    const int q4 = w2 & 3;

    if(tid < DIM){                          // stage rows + gate weights
        s_pa[tid] = g_pa[(size_t)i*DIM + tid];
        s_pb[tid] = g_pb[(size_t)i*DIM + tid];
        s_pc[tid] = g_pc[(size_t)i*DIM + tid];
        s_f4[tid] = LD(fc4w,tid,bf);
        s_f5[tid] = LD(fc5w,tid,bf);
    } else if(tid < 192){                   // stage precomputed v-row
        const int ll = tid - 128;
        s_v[ll]    = g_v[(size_t)i*DIM + ll];
        s_v[ll+64] = g_v[(size_t)i*DIM + ll + 64];
    }
    __syncthreads();

    // ---- gate phase: all 4 waves, k split in halves, exact per-half k-order ----
    const int rr = tid & 63, wv = tid >> 6;
    const int r = q4*64 + rr;
    if(wv < 2){                             // d partial (f64), half = wv
        const float4* rap = (const float4*)&g_ra[(size_t)r*DIM + wv*64];
        double d = 0.0;
#pragma unroll 4
        for(int x=0; x<16; x++){
            const float4 ra = rap[x];
            const int k = wv*64 + x*4;
            d += (double)fmaxf(s_pa[k+0]+ra.x,0.f)*(double)s_f4[k+0];
            d += (double)fmaxf(s_pa[k+1]+ra.y,0.f)*(double)s_f4[k+1];
            d += (double)fmaxf(s_pa[k+2]+ra.z,0.f)*(double)s_f4[k+2];
            d += (double)fmaxf(s_pa[k+3]+ra.w,0.f)*(double)s_f4[k+3];
        }
        s_gd[wv][rr] = d;
    } else {                                // pq partial (f32), half = wv-2
        const int hh = wv - 2;
        const float4* rbp = (const float4*)&g_rb[(size_t)r*DIM + hh*64];
        float pq = 0.f;
#pragma unroll 4
        for(int x=0; x<16; x++){
            const float4 rb = rbp[x];
            const int k = hh*64 + x*4;
            pq = fmaf(fmaxf(s_pb[k+0]+rb.x,0.f), s_f5[k+0], pq);
            pq = fmaf(fmaxf(s_pb[k+1]+rb.y,0.f), s_f5[k+1], pq);
            pq = fmaf(fmaxf(s_pb[k+2]+rb.z,0.f), s_f5[k+2], pq);
            pq = fmaf(fmaxf(s_pb[k+3]+rb.w,0.f), s_f5[k+3], pq);
        }
        s_gq[hh][rr] = pq;
    }
    __syncthreads();
    if(tid < 64){
        const double b4 = (double)LD(fc4b,0,bf);
        double sd = (s_gd[0][tid] + s_gd[1][tid]) + b4;
        float s1v = 1.f/(1.f+expf(-(float)sd));
        s_s1[tid] = (sd > 0.0) ? s1v : -s1v;
    } else if(tid < 128){
        const float b5 = LD(fc5b,0,bf);
        float pq = s_gq[0][tid-64] + s_gq[1][tid-64];
        s_p[tid-64] = 1.f/(1.f+expf(-(pq + b5)));
    }
    __syncthreads();                        // s_s1/s_p ready

    // ---- MFMA phase (r8 prefetch structure, 4 tiles; operands loaded here: 88-VGPR build) ----
    const int w = tid>>6, l = tid&63;
    const int am = l&15, quad = l>>4;
    short8 bA[4], bB[4];
#pragma unroll
    for(int ks=0; ks<4; ks++){ bA[ks]=g_bfrag[2*w][ks][l]; bB[ks]=g_bfrag[2*w+1][ks][l]; }
    const int n0 = w*32 + am, n1 = n0 + 16;
    const float v0 = s_v[n0], v1 = s_v[n1];
    const float b60 = LD(fc6b, n0, bf), b61 = LD(fc6b, n1, bf);
    float vl = s_v[l], vh = s_v[l+64];
    const float nvb = sqrtf(wred(vl*vl + vh*vh));

    int mt = q4*4;
    float4 c[8];
#pragma unroll
    for(int ks=0; ks<4; ks++){
        const float* rp = &g_rcA[((mt*4+ks)*64 + l)*8];
        c[2*ks]   = *(const float4*)rp;
        c[2*ks+1] = *(const float4*)(rp+4);
    }
    for(int mtl=0; mtl<4; mtl++){
        float4 n[8];
        if(mtl < 3){
#pragma unroll
            for(int ks=0; ks<4; ks++){
                const float* rp = &g_rcA[(((mt+1)*4+ks)*64 + l)*8];
                n[2*ks]   = *(const float4*)rp;
                n[2*ks+1] = *(const float4*)(rp+4);
            }
        }
        short8 a[4];
#pragma unroll
        for(int ks=0; ks<4; ks++){
            const float4 p0 = *(const float4*)&s_pc[ks*32 + quad*8];
            const float4 p1 = *(const float4*)&s_pc[ks*32 + quad*8 + 4];
            const float4 c0 = c[2*ks], c1 = c[2*ks+1];
            union { short8 s; unsigned u[4]; } t;
            t.u[0] = f2bf2(fmaxf(p0.x+c0.x,0.f), fmaxf(p0.y+c0.y,0.f));
            t.u[1] = f2bf2(fmaxf(p0.z+c0.z,0.f), fmaxf(p0.w+c0.w,0.f));
            t.u[2] = f2bf2(fmaxf(p1.x+c1.x,0.f), fmaxf(p1.y+c1.y,0.f));
            t.u[3] = f2bf2(fmaxf(p1.z+c1.z,0.f), fmaxf(p1.w+c1.w,0.f));
            a[ks] = t.s;
        }
        f32x4 acc0 = {0.f,0.f,0.f,0.f}, acc1 = {0.f,0.f,0.f,0.f};
#pragma unroll
        for(int ks=0; ks<4; ks++){
            acc0 = __builtin_amdgcn_mfma_f32_16x16x32_bf16(a[ks], bA[ks], acc0, 0,0,0);
            acc1 = __builtin_amdgcn_mfma_f32_16x16x32_bf16(a[ks], bB[ks], acc1, 0,0,0);
        }
#pragma unroll
        for(int q=0; q<4; q++){
            float x0 = acc0[q] + b60;
            float x1 = acc1[q] + b61;
            float ss = x0*x0 + x1*x1;
            float dv = x0*v0 + x1*v1;
#pragma unroll
            for(int o=1;o<16;o<<=1){ ss += __shfl_xor(ss,o,64); dv += __shfl_xor(dv,o,64); }
            if(am==0){
                int row = mtl*16 + quad*4 + q;
                s_st[row][w][0] = ss;
                s_st[row][w][1] = dv;
            }
        }
#pragma unroll
        for(int x=0;x<8;x++) c[x] = n[x];
        mt++;
    }
    __syncthreads();
    if(tid < 64){
        const int r2 = q4*64 + tid;
        float ss = s_st[tid][0][0]+s_st[tid][1][0]+s_st[tid][2][0]+s_st[tid][3][0];
        float dv = s_st[tid][0][1]+s_st[tid][1][1]+s_st[tid][2][1]+s_st[tid][3][1];
        float s1 = fabsf(s_s1[tid]);
        float gate = (s_s1[tid] > 0.f) ? 1.f : 0.f;
        float pp = s_p[tid];
        float nx = sqrtf(ss);
        float clipnx = fmaxf(nx, 1e-12f);
        float gvn = nx/clipnx;
        float denom = fmaxf(nvb*gvn, 1e-8f);
        float cosv = (dv/clipnx)/denom;
        float s2 = 0.5f*cosv + 0.5f;
        float sc = s1*(pp + (1.f-pp)*s2);
        g_scores[(size_t)i*RN + r2] = sc * gate;
    }
}

// ---------------- C: pooled max + reg mean (branchless prefetchable sum) ----------------
__global__ void k_fin(float* __restrict__ out, const void* __restrict__ pad,
                      const int* __restrict__ ws){
    const bool w64 = (ws[2] & 2) != 0;
    const int blk = blockIdx.x, tid = threadIdx.x;
    const int w = tid>>6, l = tid&63;
    __shared__ float s[4];
    if(blk < 32){
        __shared__ float s_padf[MAXPV];
        if(tid < MAXPV) s_padf[tid] = LDI(pad, (size_t)blk*MAXPV + tid, w64) ? 1.f : 0.f;
        __syncthreads();
        // Unconditional loads (compiler can batch-issue); adding +0.f for masked
        // rows is exact: all scores are >= +0 and ssum starts at +0.
        float ssum = 0.f;
#pragma unroll 10
        for(int pv=0; pv<MAXPV; pv++){
            float v = g_scores[((size_t)blk*MAXPV + pv)*RN + tid];
            ssum += (s_padf[pv] != 0.f) ? v : 0.f;
        }
        float sc = ssum / g_rmask[tid];
        float m = wmax(sc);
        if(l==0) s[w]=m;
        __syncthreads();
        if(tid==0) out[blk] = fmaxf(fmaxf(s[0],s[1]), fmaxf(s[2],s[3]));
    } else {
        float v = g_regp[tid];
        v = wred(v);
        if(l==0) s[w]=v;
        __syncthreads();
        if(tid==0) out[32] = (s[0]+s[1]+s[2]+s[3]) / (float)(RN*PN);
    }
}

extern "C" void kernel_launch(void* const* d_in, const int* in_sizes, int n_in,
                              void* d_out, int out_size, void* d_ws, size_t ws_size,
                              hipStream_t stream){
    int map[18]; for(int i=0;i<18;i++) map[i]=i;
    if(n_in>=18 && in_sizes[0]==6400000){
        const int a[18] = {14,17,16,13,15,0,2,1,4,3,6,5,8,7,10,9,12,11};
        for(int i=0;i<18;i++) map[i]=a[i];
    }
    const void* prop = d_in[map[0]];
    const void* val  = d_in[map[1]];
    const void* same = d_in[map[2]];
    const void* pad  = d_in[map[3]];
    const void* rule = d_in[map[4]];
    const void* ent  = d_in[map[5]];
    const void* fc1w = d_in[map[6]];
    const void* fc1b = d_in[map[7]];
    const void* fc2w = d_in[map[8]];
    const void* fc2b = d_in[map[9]];
    const void* fc3w = d_in[map[10]];
    const void* fc3b = d_in[map[11]];
    const void* fc4w = d_in[map[12]];
    const void* fc4b = d_in[map[13]];
    const void* fc5w = d_in[map[14]];
    const void* fc5b = d_in[map[15]];
    const void* fc6w = d_in[map[16]];
    const void* fc6b = d_in[map[17]];

    hipMemsetAsync(d_ws, 0, 16, stream);   // zero worklist counters + flags
    k_pre<<<779, 256, 0, stream>>>(ent, rule, prop, val, same, pad, fc6w,
                                   fc1w, fc2w, fc3w, fc1b, fc2b, fc3b, (int*)d_ws);
    // 4*nsame + 2*ndiff <= 4*(nsame+ndiff) <= 6400, so 64+6400 blocks always cover.
    k_score<<<64 + 6400, 256, 0, stream>>>(fc4w, fc4b, fc5w, fc5b, fc6b,
                                           (const int*)d_ws);
    k_fin<<<33, 256, 0, stream>>>((float*)d_out, pad, (const int*)d_ws);
}

// Round 13
// 176.280 us; speedup vs baseline: 1.1108x; 1.0374x over previous
//
#include <hip/hip_runtime.h>
#include <hip/hip_bf16.h>

#define BATCH 32
#define MAXPV 50
#define RN 256
#define PN 256
#define DIM 128
#define NI (BATCH*MAXPV)   // 1600 (b,pv) pairs

typedef unsigned short u16;
typedef __attribute__((ext_vector_type(8))) short short8;
typedef __attribute__((ext_vector_type(4))) float f32x4;

// ---- intermediates in the code object ----
__device__ float g_pa[NI*DIM], g_pb[NI*DIM], g_pc[NI*DIM];
__device__ float g_pp1[PN*DIM];
__device__ __attribute__((aligned(16))) float g_v[NI*DIM];    // normalized value rows
__device__ __attribute__((aligned(16))) float g_ra[RN*DIM];   // row-major [r][k]
__device__ __attribute__((aligned(16))) float g_rb[RN*DIM];   // row-major [r][k]
__device__ float g_rmask[RN], g_regp[RN];
__device__ float g_scores[(size_t)NI*RN];            // per-(i,r) contribution (pad rows only valid)
__device__ short8 g_bfrag[8][4][64];                 // fc6 B-frags [nt][ks][lane]
__device__ __attribute__((aligned(16))) float g_rcA[16*4*64*8]; // rc in MFMA-A layout [mt][ks][lane][8]

// d_ws layout (ints): [0]=nsame [1]=ndiff [2]=flags(bit0=bf16,bit1=i64) [3]=unused
// [4..1604): int wls[1600] = {i}   [1604..3204): int wld[1600] = {i}
#define WS_WLS(ws)  ((ws)+4)
#define WS_WLD(ws)  ((ws)+4+1600)

__device__ __forceinline__ float bf2f(u16 u){ return __uint_as_float(((unsigned)u)<<16); }
__device__ __forceinline__ float LD(const void* p, size_t i, bool bf){
    return bf ? bf2f(((const u16*)p)[i]) : ((const float*)p)[i];
}
__device__ __forceinline__ int LDI(const void* p, size_t i, bool w64){
    return w64 ? (int)((const long long*)p)[i] : ((const int*)p)[i];
}
__device__ __forceinline__ short f2bf(float f){
    unsigned u = __float_as_uint(f);
    u = (u + 0x7FFFu + ((u>>16)&1u)) >> 16;
    return (short)u;
}
__device__ __forceinline__ unsigned f2bf2(float x, float y){
    float2 f; f.x=x; f.y=y;
    __hip_bfloat162 h = __float22bfloat162_rn(f);      // v_cvt_pk_bf16_f32
    union { __hip_bfloat162 h; unsigned u; } c; c.h=h; return c.u;
}
// ---- per-block inline dtype detection (wave-uniform, ~6 insts) ----
__device__ __forceinline__ bool det_bf16(const void* ent){
    int l = threadIdx.x & 63;
    u16 v = ((const u16*)ent)[(size_t)2*(l*4)*977];    // max idx 492,408: safe both dtypes
    int e = (v>>7)&0xFF;
    return __popcll(__ballot(e>=120 && e<=133)) >= 48; // bf16 ~64/64, fp32 ~6/64
}
__device__ __forceinline__ bool det_i64(const void* prop){
    int l = threadIdx.x & 63;
    bool z = (l<32) ? (((const unsigned*)prop)[2*l+1]==0u) : false;
    return __popcll(__ballot(z)) >= 30;                // int64: 32/32 odd words zero
}
__device__ __forceinline__ float wred(float v){
#pragma unroll
    for(int o=32;o;o>>=1) v += __shfl_xor(v,o,64);
    return v;
}
__device__ __forceinline__ double wredd(double v){
#pragma unroll
    for(int o=32;o;o>>=1) v += __shfl_xor(v,o,64);
    return v;
}
__device__ __forceinline__ float wmax(float v){
#pragma unroll
    for(int o=32;o;o>>=1) v = fmaxf(v,__shfl_xor(v,o,64));
    return v;
}

// ---------------- A: fused gather+l2norm+row-matmuls + compaction + v-rows ----------------
// [0,100) pa | [100,200) pb | [200,300) pc | [300,316) ra | [316,332) rb
// [332,348) rcA | [348,364) pp1 | [364,372) bfrag pack (+init/flags on nt==0)
// [372,379) worklist compaction | [379,779) v-row gather+normalize
__global__ __launch_bounds__(256) void k_pre(
    const void* __restrict__ ent, const void* __restrict__ rule,
    const void* __restrict__ prop, const void* __restrict__ val,
    const void* __restrict__ same, const void* __restrict__ pad,
    const void* __restrict__ fc6w,
    const void* __restrict__ fc1w, const void* __restrict__ fc2w, const void* __restrict__ fc3w,
    const void* __restrict__ fc1b, const void* __restrict__ fc2b, const void* __restrict__ fc3b,
    int* __restrict__ ws){
    const bool bf = det_bf16(ent);
    const int blk = blockIdx.x, tid = threadIdx.x;
    if(blk >= 379){                                   // ---- v-row gather + l2norm ----
        const bool w64 = det_i64(prop);
        const int row = (blk-379)*4 + (tid>>6);
        const int l = tid & 63;
        size_t off = (size_t)LDI(val,row,w64)*DIM;
        float a = LD(ent,off+l,bf), b = LD(ent,off+l+64,bf);
        float n = fmaxf(sqrtf((float)wredd((double)a*a+(double)b*b)), 1e-12f);
        g_v[(size_t)row*DIM+l]=a/n; g_v[(size_t)row*DIM+l+64]=b/n;
        return;
    }
    if(blk >= 372){                                   // ---- worklist compaction ----
        const bool w64 = det_i64(prop);
        int i = (blk-372)*256 + tid;
        if(i < NI){
            int pd = LDI(pad,i,w64);
            if(pd==1){
                int sm = LDI(same,i,w64);
                if(sm==1){
                    int x = atomicAdd(ws+0,1);
                    WS_WLS(ws)[x] = i;
                } else {
                    int x = atomicAdd(ws+1,1);
                    WS_WLD(ws)[x] = i;
                }
            }
        }
        return;
    }
    if(blk >= 364){                                   // bfrag pack + accum init + flags
        int nt = blk-364;
        int ks = tid>>6, lane = tid&63;
        int n = nt*16 + (lane&15);
        int k0 = ks*32 + (lane>>4)*8;
        short8 v;
#pragma unroll
        for(int j=0;j<8;j++) v[j] = f2bf(LD(fc6w,(size_t)(k0+j)*DIM + n, bf));
        g_bfrag[nt][ks][lane] = v;
        if(nt==0){
            g_rmask[tid] = 1.f; g_regp[tid] = 0.f;
            const bool w64 = det_i64(prop);
            if(tid==0) ws[2] = (bf?1:0) | (w64?2:0);
        }
        return;
    }
    __shared__ float s_w[64*DIM];       // 32 KB (k-half of weights, fp32)
    __shared__ __attribute__((aligned(16))) float s_in[16*DIM]; // 8 KB
    __shared__ float s_bias[DIM];
    const void* w; size_t woff=0; const void* bptr=nullptr;
    float* out=nullptr; int row0; int mode=0; int srcsel;
    if(blk < 300){
        int wsel = blk/100; row0 = (blk%100)*16; srcsel = 0;
        w   = (wsel==0)?fc1w:(wsel==1)?fc2w:fc3w;
        out = (wsel==0)?g_pa:(wsel==1)?g_pb:g_pc;
    } else if(blk < 348){
        int rblk = blk-300; int wsel = rblk>>4; row0 = (rblk&15)*16; srcsel = 1;
        w    = (wsel==0)?fc1w:(wsel==1)?fc2w:fc3w;
        bptr = (wsel==0)?fc1b:(wsel==1)?fc2b:fc3b;
        woff = DIM*DIM; mode = wsel+1;
    } else { row0=(blk-348)*16; w=fc1w; out=g_pp1; srcsel=2; }
    // gather + l2norm the 16 input rows straight into LDS
    const bool w64 = (srcsel==0) ? det_i64(prop) : false;
    {
        const int l = tid & 63;
        for(int it=0; it<4; it++){
            int lr = it*4 + (tid>>6);
            int row = row0 + lr;
            const void* src; size_t off;
            if(srcsel==0){ src=ent;  off=(size_t)LDI(prop,row,w64)*DIM; }
            else if(srcsel==1){ src=rule; off=(size_t)row*DIM; }
            else { src=ent; off=(size_t)row*DIM; }
            float a = LD(src,off+l,bf), b = LD(src,off+l+64,bf);
            float n = fmaxf(sqrtf((float)wredd((double)a*a+(double)b*b)), 1e-12f);
            s_in[lr*DIM+l]=a/n; s_in[lr*DIM+l+64]=b/n;
        }
    }
    if(tid<DIM) s_bias[tid] = bptr ? LD(bptr,tid,bf) : 0.f;
    const int j = tid & 127;
    const int rb8 = (tid>>7)*8;
    double acc[8] = {0,0,0,0,0,0,0,0};
    for(int half=0; half<2; half++){
        __syncthreads();
        for(int t=tid; t<64*DIM; t+=256)
            s_w[t] = LD(w, woff + (size_t)(half*64 + (t>>7))*DIM + (t&127), bf);
        __syncthreads();
        for(int k=0;k<64;k+=4){                       // float4 s_in reads, same k-order
            const float w0 = s_w[(k+0)*DIM + j];
            const float w1 = s_w[(k+1)*DIM + j];
            const float w2 = s_w[(k+2)*DIM + j];
            const float w3 = s_w[(k+3)*DIM + j];
#pragma unroll
            for(int rr=0;rr<8;rr++){
                const float4 in4 = *(const float4*)&s_in[(rb8+rr)*DIM + half*64 + k];
                acc[rr] += (double)in4.x*(double)w0;
                acc[rr] += (double)in4.y*(double)w1;
                acc[rr] += (double)in4.z*(double)w2;
                acc[rr] += (double)in4.w*(double)w3;
            }
        }
    }
    const double bj = (double)s_bias[j];
#pragma unroll
    for(int rr=0;rr<8;rr++){
        const int row = row0 + rb8 + rr;
        const float vv = (float)(bj + acc[rr]);
        if(mode==0)      out[(size_t)row*DIM + j] = vv;
        else if(mode==1) g_ra[(size_t)row*DIM + j] = vv;   // row-major
        else if(mode==2) g_rb[(size_t)row*DIM + j] = vv;   // row-major
        else {           // rcA scatter: row in [0,256), k=j
            int mt=row>>4, am=row&15, ks=j>>5, quad=(j>>3)&3, jj=j&7;
            g_rcA[((mt*4+ks)*64 + quad*16+am)*8 + jj] = vv;
        }
    }
}

// ---------------- B: fused gates + MFMA scoring (grid-driven, 4-wave gate split) ----------------
// [0,64): pi items | [64, 64+4*nsame): MFMA quarters | then 2*ndiff diff half-items
__global__ __launch_bounds__(256) void k_score(
    const void* __restrict__ fc4w, const void* __restrict__ fc4b,
    const void* __restrict__ fc5w, const void* __restrict__ fc5b,
    const void* __restrict__ fc6b, const int* __restrict__ ws){
    const int blk = blockIdx.x, tid = threadIdx.x;
    const int fl = ws[2];
    const bool bf = fl & 1;
    if(blk < 64){                                      // ---- pi item ----
        __shared__ float s_a[4][DIM];
        __shared__ double s_pf4[DIM];
        const int i0 = blk*4;
        if(tid<DIM) s_pf4[tid]=(double)LD(fc4w,tid,bf);
        for(int t=tid; t<4*DIM; t+=256){
            int ii=t>>7, k=t&127;
            s_a[ii][k] = g_pp1[(size_t)(i0+ii)*DIM+k];
        }
        __syncthreads();
        const int r = tid;
        const float4* rap = (const float4*)&g_ra[(size_t)r*DIM];
        double d0=0.0, d1=0.0, d2=0.0, d3=0.0;
#pragma unroll 4
        for(int x=0; x<32; x++){                       // k = 4x..4x+3, ascending
            const float4 ra = rap[x];
#pragma unroll
            for(int cc=0; cc<4; cc++){
                const int k = x*4 + cc;
                const float rav = (cc==0)?ra.x:(cc==1)?ra.y:(cc==2)?ra.z:ra.w;
                const double f4k = s_pf4[k];
                d0 += (double)fmaxf(s_a[0][k]+rav,0.f)*f4k;
                d1 += (double)fmaxf(s_a[1][k]+rav,0.f)*f4k;
                d2 += (double)fmaxf(s_a[2][k]+rav,0.f)*f4k;
                d3 += (double)fmaxf(s_a[3][k]+rav,0.f)*f4k;
            }
        }
        const double b4 = (double)LD(fc4b,0,bf);
        double d[4] = {d0,d1,d2,d3};
        float mask_sum = 0.f, reg_sum = 0.f;
#pragma unroll
        for(int ii=0;ii<4;ii++){
            int p = i0 + ii;
            double sd = d[ii] + b4;
            float piv = 1.f/(1.f+expf(-(float)sd));
            if(sd > 0.0) mask_sum += piv;              // piv>0.5 <=> sd>0
            float eff = (p==r) ? piv : (1.f - piv);
            float wgt = (p==r) ? (float)RN : 1.f;
            reg_sum += -logf(eff + 1e-8f)*wgt;
        }
        atomicAdd(&g_rmask[r], mask_sum);
        atomicAdd(&g_regp[r], reg_sum);
        return;
    }
    int w2 = blk - 64;
    const int ns4 = ws[0]*4;

    __shared__ float s_pa[DIM], s_pb[DIM], s_pc[DIM], s_v[DIM], s_f4[DIM], s_f5[DIM];
    __shared__ double s_gd[2][64];
    __shared__ float s_gq[2][64];
    __shared__ double s_pd[2][128];
    __shared__ float s_s1[64], s_p[64];
    __shared__ float s_st[64][4][2];       // 2 KB

    if(w2 >= ns4){                                     // ---- diff half-item (128 r, k split) ----
        int t2 = w2 - ns4;
        if(t2 >= 2*ws[1]) return;
        const int i = WS_WLD(ws)[t2>>1];
        const int sub = t2 & 1;
        if(tid < 128){
            s_pa[tid] = g_pa[(size_t)i*DIM + tid];
            s_f4[tid] = LD(fc4w,tid,bf);
        }
        __syncthreads();
        const int rr = tid & 127, half = tid >> 7;
        const int r = sub*128 + rr;
        const float4* rap = (const float4*)&g_ra[(size_t)r*DIM + half*64];
        double d = 0.0;
#pragma unroll 4
        for(int x=0; x<16; x++){                       // k = half*64 + 4x.., ascending
            const float4 ra = rap[x];
            const int k = half*64 + x*4;
            d += (double)fmaxf(s_pa[k+0]+ra.x,0.f)*(double)s_f4[k+0];
            d += (double)fmaxf(s_pa[k+1]+ra.y,0.f)*(double)s_f4[k+1];
            d += (double)fmaxf(s_pa[k+2]+ra.z,0.f)*(double)s_f4[k+2];
            d += (double)fmaxf(s_pa[k+3]+ra.w,0.f)*(double)s_f4[k+3];
        }
        s_pd[half][rr] = d;
        __syncthreads();
        if(tid < 128){
            const double b4 = (double)LD(fc4b,0,bf);
            double sd = (s_pd[0][tid] + s_pd[1][tid]) + b4;
            float s1v = 1.f/(1.f+expf(-(float)sd));
            g_scores[(size_t)i*RN + sub*128 + tid] = (sd > 0.0) ? (1.f - s1v) : 0.f;
        }
        return;
    }

    // ---- MFMA quarter: q4 in [0,4), covers mt = q4*4..q4*4+3, rows r = q4*64..+64 ----
    const int i = WS_WLS(ws)[w2>>2];
    const int q4 = w2 & 3;

    if(tid < DIM){                          // stage rows + gate weights
        s_pa[tid] = g_pa[(size_t)i*DIM + tid];
        s_pb[tid] = g_pb[(size_t)i*DIM + tid];
        s_pc[tid] = g_pc[(size_t)i*DIM + tid];
        s_f4[tid] = LD(fc4w,tid,bf);
        s_f5[tid] = LD(fc5w,tid,bf);
    } else if(tid < 192){                   // stage precomputed v-row
        const int ll = tid - 128;
        s_v[ll]    = g_v[(size_t)i*DIM + ll];
        s_v[ll+64] = g_v[(size_t)i*DIM + ll + 64];
    }
    __syncthreads();

    // ---- gate phase: all 4 waves, k split in halves, exact per-half k-order ----
    const int rr = tid & 63, wv = tid >> 6;
    const int r = q4*64 + rr;
    if(wv < 2){                             // d partial (f64), half = wv
        const float4* rap = (const float4*)&g_ra[(size_t)r*DIM + wv*64];
        double d = 0.0;
#pragma unroll 4
        for(int x=0; x<16; x++){
            const float4 ra = rap[x];
            const int k = wv*64 + x*4;
            d += (double)fmaxf(s_pa[k+0]+ra.x,0.f)*(double)s_f4[k+0];
            d += (double)fmaxf(s_pa[k+1]+ra.y,0.f)*(double)s_f4[k+1];
            d += (double)fmaxf(s_pa[k+2]+ra.z,0.f)*(double)s_f4[k+2];
            d += (double)fmaxf(s_pa[k+3]+ra.w,0.f)*(double)s_f4[k+3];
        }
        s_gd[wv][rr] = d;
    } else {                                // pq partial (f32), half = wv-2
        const int hh = wv - 2;
        const float4* rbp = (const float4*)&g_rb[(size_t)r*DIM + hh*64];
        float pq = 0.f;
#pragma unroll 4
        for(int x=0; x<16; x++){
            const float4 rb = rbp[x];
            const int k = hh*64 + x*4;
            pq = fmaf(fmaxf(s_pb[k+0]+rb.x,0.f), s_f5[k+0], pq);
            pq = fmaf(fmaxf(s_pb[k+1]+rb.y,0.f), s_f5[k+1], pq);
            pq = fmaf(fmaxf(s_pb[k+2]+rb.z,0.f), s_f5[k+2], pq);
            pq = fmaf(fmaxf(s_pb[k+3]+rb.w,0.f), s_f5[k+3], pq);
        }
        s_gq[hh][rr] = pq;
    }
    __syncthreads();
    if(tid < 64){
        const double b4 = (double)LD(fc4b,0,bf);
        double sd = (s_gd[0][tid] + s_gd[1][tid]) + b4;
        float s1v = 1.f/(1.f+expf(-(float)sd));
        s_s1[tid] = (sd > 0.0) ? s1v : -s1v;
    } else if(tid < 128){
        const float b5 = LD(fc5b,0,bf);
        float pq = s_gq[0][tid-64] + s_gq[1][tid-64];
        s_p[tid-64] = 1.f/(1.f+expf(-(pq + b5)));
    }
    __syncthreads();                        // s_s1/s_p ready

    // ---- MFMA phase: direct c-loads (no prefetch dbuf) -> ~32 fewer VGPRs,
    //      higher block concurrency hides rcA L2 latency across blocks ----
    const int w = tid>>6, l = tid&63;
    const int am = l&15, quad = l>>4;
    short8 bA[4], bB[4];
#pragma unroll
    for(int ks=0; ks<4; ks++){ bA[ks]=g_bfrag[2*w][ks][l]; bB[ks]=g_bfrag[2*w+1][ks][l]; }
    const int n0 = w*32 + am, n1 = n0 + 16;
    const float v0 = s_v[n0], v1 = s_v[n1];
    const float b60 = LD(fc6b, n0, bf), b61 = LD(fc6b, n1, bf);
    float vl = s_v[l], vh = s_v[l+64];
    const float nvb = sqrtf(wred(vl*vl + vh*vh));

    for(int mtl=0; mtl<4; mtl++){
        const int mt = q4*4 + mtl;
        float4 c[8];
#pragma unroll
        for(int ks=0; ks<4; ks++){
            const float* rp = &g_rcA[((mt*4+ks)*64 + l)*8];
            c[2*ks]   = *(const float4*)rp;
            c[2*ks+1] = *(const float4*)(rp+4);
        }
        short8 a[4];
#pragma unroll
        for(int ks=0; ks<4; ks++){
            const float4 p0 = *(const float4*)&s_pc[ks*32 + quad*8];
            const float4 p1 = *(const float4*)&s_pc[ks*32 + quad*8 + 4];
            const float4 c0 = c[2*ks], c1 = c[2*ks+1];
            union { short8 s; unsigned u[4]; } t;
            t.u[0] = f2bf2(fmaxf(p0.x+c0.x,0.f), fmaxf(p0.y+c0.y,0.f));
            t.u[1] = f2bf2(fmaxf(p0.z+c0.z,0.f), fmaxf(p0.w+c0.w,0.f));
            t.u[2] = f2bf2(fmaxf(p1.x+c1.x,0.f), fmaxf(p1.y+c1.y,0.f));
            t.u[3] = f2bf2(fmaxf(p1.z+c1.z,0.f), fmaxf(p1.w+c1.w,0.f));
            a[ks] = t.s;
        }
        f32x4 acc0 = {0.f,0.f,0.f,0.f}, acc1 = {0.f,0.f,0.f,0.f};
#pragma unroll
        for(int ks=0; ks<4; ks++){
            acc0 = __builtin_amdgcn_mfma_f32_16x16x32_bf16(a[ks], bA[ks], acc0, 0,0,0);
            acc1 = __builtin_amdgcn_mfma_f32_16x16x32_bf16(a[ks], bB[ks], acc1, 0,0,0);
        }
#pragma unroll
        for(int q=0; q<4; q++){
            float x0 = acc0[q] + b60;
            float x1 = acc1[q] + b61;
            float ss = x0*x0 + x1*x1;
            float dv = x0*v0 + x1*v1;
#pragma unroll
            for(int o=1;o<16;o<<=1){ ss += __shfl_xor(ss,o,64); dv += __shfl_xor(dv,o,64); }
            if(am==0){
                int row = mtl*16 + quad*4 + q;
                s_st[row][w][0] = ss;
                s_st[row][w][1] = dv;
            }
        }
    }
    __syncthreads();
    if(tid < 64){
        const int r2 = q4*64 + tid;
        float ss = s_st[tid][0][0]+s_st[tid][1][0]+s_st[tid][2][0]+s_st[tid][3][0];
        float dv = s_st[tid][0][1]+s_st[tid][1][1]+s_st[tid][2][1]+s_st[tid][3][1];
        float s1 = fabsf(s_s1[tid]);
        float gate = (s_s1[tid] > 0.f) ? 1.f : 0.f;
        float pp = s_p[tid];
        float nx = sqrtf(ss);
        float clipnx = fmaxf(nx, 1e-12f);
        float gvn = nx/clipnx;
        float denom = fmaxf(nvb*gvn, 1e-8f);
        float cosv = (dv/clipnx)/denom;
        float s2 = 0.5f*cosv + 0.5f;
        float sc = s1*(pp + (1.f-pp)*s2);
        g_scores[(size_t)i*RN + r2] = sc * gate;
    }
}

// ---------------- C: pooled max + reg mean (branchless prefetchable sum) ----------------
__global__ void k_fin(float* __restrict__ out, const void* __restrict__ pad,
                      const int* __restrict__ ws){
    const bool w64 = (ws[2] & 2) != 0;
    const int blk = blockIdx.x, tid = threadIdx.x;
    const int w = tid>>6, l = tid&63;
    __shared__ float s[4];
    if(blk < 32){
        __shared__ float s_padf[MAXPV];
        if(tid < MAXPV) s_padf[tid] = LDI(pad, (size_t)blk*MAXPV + tid, w64) ? 1.f : 0.f;
        __syncthreads();
        // Unconditional loads (compiler can batch-issue); adding +0.f for masked
        // rows is exact: all scores are >= +0 and ssum starts at +0.
        float ssum = 0.f;
#pragma unroll 10
        for(int pv=0; pv<MAXPV; pv++){
            float v = g_scores[((size_t)blk*MAXPV + pv)*RN + tid];
            ssum += (s_padf[pv] != 0.f) ? v : 0.f;
        }
        float sc = ssum / g_rmask[tid];
        float m = wmax(sc);
        if(l==0) s[w]=m;
        __syncthreads();
        if(tid==0) out[blk] = fmaxf(fmaxf(s[0],s[1]), fmaxf(s[2],s[3]));
    } else {
        float v = g_regp[tid];
        v = wred(v);
        if(l==0) s[w]=v;
        __syncthreads();
        if(tid==0) out[32] = (s[0]+s[1]+s[2]+s[3]) / (float)(RN*PN);
    }
}

extern "C" void kernel_launch(void* const* d_in, const int* in_sizes, int n_in,
                              void* d_out, int out_size, void* d_ws, size_t ws_size,
                              hipStream_t stream){
    int map[18]; for(int i=0;i<18;i++) map[i]=i;
    if(n_in>=18 && in_sizes[0]==6400000){
        const int a[18] = {14,17,16,13,15,0,2,1,4,3,6,5,8,7,10,9,12,11};
        for(int i=0;i<18;i++) map[i]=a[i];
    }
    const void* prop = d_in[map[0]];
    const void* val  = d_in[map[1]];
    const void* same = d_in[map[2]];
    const void* pad  = d_in[map[3]];
    const void* rule = d_in[map[4]];
    const void* ent  = d_in[map[5]];
    const void* fc1w = d_in[map[6]];
    const void* fc1b = d_in[map[7]];
    const void* fc2w = d_in[map[8]];
    const void* fc2b = d_in[map[9]];
    const void* fc3w = d_in[map[10]];
    const void* fc3b = d_in[map[11]];
    const void* fc4w = d_in[map[12]];
    const void* fc4b = d_in[map[13]];
    const void* fc5w = d_in[map[14]];
    const void* fc5b = d_in[map[15]];
    const void* fc6w = d_in[map[16]];
    const void* fc6b = d_in[map[17]];

    hipMemsetAsync(d_ws, 0, 16, stream);   // zero worklist counters + flags
    k_pre<<<779, 256, 0, stream>>>(ent, rule, prop, val, same, pad, fc6w,
                                   fc1w, fc2w, fc3w, fc1b, fc2b, fc3b, (int*)d_ws);
    // 4*nsame + 2*ndiff <= 4*(nsame+ndiff) <= 6400, so 64+6400 blocks always cover.
    k_score<<<64 + 6400, 256, 0, stream>>>(fc4w, fc4b, fc5w, fc5b, fc6b,
                                           (const int*)d_ws);
    k_fin<<<33, 256, 0, stream>>>((float*)d_out, pad, (const int*)d_ws);
}